// Round 6
// baseline (347.139 us; speedup 1.0000x reference)
//
#include <hip/hip_runtime.h>

#define BIG_F 1e10f
constexpr int B = 16;
constexpr int N = 4096;
constexpr int QPT = 8;      // queries per thread (2048 queries per block)
constexpr int SCHUNK = 128; // set points per block (N/SCHUNK = 32 chunks)
constexpr int NBLOCKS = (N / 2048) * (N / SCHUNK) * B * 2;  // 2048

// pack layout per set point j: { -2*s0, -2*s1, -2*s2, s·s + (valid ? 0 : BIG) }
// dist(q, j) = qq + dot(q, pack.xyz) + pack.w; qq hoists out of the min.

__global__ __launch_bounds__(256) void prep_kernel(
    const float* __restrict__ x, const float* __restrict__ y,
    const int* __restrict__ mask,
    float4* __restrict__ packx, float4* __restrict__ packy,
    unsigned* __restrict__ minarr, unsigned* __restrict__ counter)
{
    int idx = blockIdx.x * 256 + threadIdx.x;   // 0 .. B*N-1
    int b = idx >> 12;                          // N == 4096
    int j = idx & (N - 1);
    float madd = mask[idx] ? 0.0f : BIG_F;

    const float* xb = x + (size_t)b * 3 * N;
    float x0 = xb[j], x1 = xb[N + j], x2 = xb[2 * N + j];
    float4 px;
    px.x = -2.0f * x0; px.y = -2.0f * x1; px.z = -2.0f * x2;
    px.w = fmaf(x2, x2, fmaf(x1, x1, x0 * x0)) + madd;
    packx[idx] = px;

    const float* yb = y + (size_t)b * 3 * N;
    float y0 = yb[j], y1 = yb[N + j], y2 = yb[2 * N + j];
    float4 py;
    py.x = -2.0f * y0; py.y = -2.0f * y1; py.z = -2.0f * y2;
    py.w = fmaf(y2, y2, fmaf(y1, y1, y0 * y0)) + madd;
    packy[idx] = py;

    // fused init (no extra memset dispatches)
    minarr[idx] = 0xFFFFFFFFu;
    minarr[idx + B * N] = 0xFFFFFFFFu;
    if (idx == 0) counter[0] = 0u;
}

// monotonic float->uint key: preserves order for ALL floats (incl. tiny negatives)
__device__ __forceinline__ unsigned enc_key(float f) {
    unsigned bits = __float_as_uint(f);
    return (bits & 0x80000000u) ? ~bits : (bits | 0x80000000u);
}
__device__ __forceinline__ float dec_key(unsigned key) {
    unsigned bits = (key & 0x80000000u) ? (key ^ 0x80000000u) : ~key;
    return __uint_as_float(bits);
}

__global__ __launch_bounds__(256) void chamfer_main(
    const float* __restrict__ x, const float* __restrict__ y,
    const float4* __restrict__ packx, const float4* __restrict__ packy,
    const int* __restrict__ mask,
    unsigned* __restrict__ minarr, unsigned* __restrict__ counter,
    float* __restrict__ out)
{
    const int qt  = blockIdx.x & 1;   // query tile 0..1 (2048 queries each)
    const int sc  = blockIdx.x >> 1;  // set chunk 0..31 (128 set points each)
    const int b   = blockIdx.y;
    const int dir = blockIdx.z;

    const float*  Q = (dir == 0 ? x : y) + (size_t)b * 3 * N;
    const float4* W = (dir == 0 ? packy : packx) + (size_t)b * N + sc * SCHUNK;
    unsigned* Mrow = minarr + (((dir * B) + b) << 12) + qt * 2048 + threadIdx.x;

    float qx[QPT], qy[QPT], qz[QPT], m[QPT];
    const int qbase = qt * 2048 + threadIdx.x;
#pragma unroll
    for (int k = 0; k < QPT; ++k) {
        int q = qbase + k * 256;
        qx[k] = Q[q]; qy[k] = Q[N + q]; qz[k] = Q[2 * N + q];
        m[k] = 1e30f;
    }

    auto do_point = [&](const float4 wp) {
#pragma unroll
        for (int k = 0; k < QPT; ++k)
            m[k] = fminf(m[k],
                fmaf(qx[k], wp.x, fmaf(qy[k], wp.y, fmaf(qz[k], wp.z, wp.w))));
    };

    // software pipeline, prefetch distance 8 points (two rotating 4-point
    // SGPR buffers; wave-uniform scalar loads)
    float4 a0 = W[0], a1 = W[1], a2 = W[2], a3 = W[3];
    float4 b0 = W[4], b1 = W[5], b2 = W[6], b3 = W[7];
    for (int p = 0; p < SCHUNK - 8; p += 8) {
        float4 n0 = W[p + 8], n1 = W[p + 9], n2 = W[p + 10], n3 = W[p + 11];
        do_point(a0); do_point(a1); do_point(a2); do_point(a3);
        a0 = n0; a1 = n1; a2 = n2; a3 = n3;
        n0 = W[p + 12]; n1 = W[p + 13]; n2 = W[p + 14]; n3 = W[p + 15];
        do_point(b0); do_point(b1); do_point(b2); do_point(b3);
        b0 = n0; b1 = n1; b2 = n2; b3 = n3;
    }
    do_point(a0); do_point(a1); do_point(a2); do_point(a3);
    do_point(b0); do_point(b1); do_point(b2); do_point(b3);

#pragma unroll
    for (int k = 0; k < QPT; ++k) {
        float qq = fmaf(qz[k], qz[k], fmaf(qy[k], qy[k], qx[k] * qx[k]));
        atomicMin(Mrow + k * 256, enc_key(qq + m[k]));
    }

    // ---- fused finalize: last block to finish does the reduction ----
    __threadfence();
    __syncthreads();
    __shared__ unsigned last;
    if (threadIdx.x == 0) last = atomicAdd(counter, 1u);
    __syncthreads();
    if (last != (unsigned)(NBLOCKS - 1)) return;

    __threadfence();  // acquire: make all blocks' atomicMin results visible
    const int wv = threadIdx.x >> 6, ln = threadIdx.x & 63;
    __shared__ float rowres[32];
    for (int r = wv; r < 32; r += 4) {          // r = dir*16 + batch
        const unsigned* Mr = minarr + ((size_t)r << 12);
        const int* mrow = mask + (r & 15) * N;
        float s = 0.0f, c = 0.0f;
        for (int q2 = ln; q2 < N; q2 += 64) {
            int mk = mrow[q2];
            float v = dec_key(Mr[q2]);
            if (mk) { s += v; c += 1.0f; }
        }
        for (int off = 32; off > 0; off >>= 1) {
            s += __shfl_down(s, off);
            c += __shfl_down(c, off);
        }
        if (ln == 0) rowres[r] = s / c;
    }
    __syncthreads();
    if (threadIdx.x == 0) {
        float t = 0.0f;
        for (int r = 0; r < 32; ++r) t += rowres[r];
        out[0] = t * (1.0f / (float)B);
    }
}

extern "C" void kernel_launch(void* const* d_in, const int* in_sizes, int n_in,
                              void* d_out, int out_size, void* d_ws, size_t ws_size,
                              hipStream_t stream) {
    const float* x    = (const float*)d_in[0];
    const float* y    = (const float*)d_in[1];
    const int*   mask = (const int*)d_in[2];

    float4*   packx   = (float4*)d_ws;
    float4*   packy   = packx + (size_t)B * N;
    unsigned* minarr  = (unsigned*)(packy + (size_t)B * N);  // 2*B*N uints
    unsigned* counter = minarr + (size_t)2 * B * N;

    prep_kernel<<<dim3(B * N / 256), 256, 0, stream>>>(
        x, y, mask, packx, packy, minarr, counter);
    chamfer_main<<<dim3((N / 2048) * (N / SCHUNK), B, 2), 256, 0, stream>>>(
        x, y, packx, packy, mask, minarr, counter, (float*)d_out);
}

// Round 7
// 103.743 us; speedup vs baseline: 3.3461x; 3.3461x over previous
//
#include <hip/hip_runtime.h>

#define BIG_F 1e10f
constexpr int B = 16;
constexpr int N = 4096;
constexpr int QPT = 8;       // 256 threads x 8 = 2048 queries per block
constexpr int SCHUNK = 256;  // set points staged in LDS per block
constexpr int NSC = N / SCHUNK;  // 16 chunks

// pack per set point j: { -2*s0, -2*s1, -2*s2, s.s + (valid ? 0 : BIG) }
// dist(q,j) = qq + dot(q, pack.xyz) + pack.w; qq hoists out of the min.

__global__ __launch_bounds__(256) void chamfer_main(
    const float* __restrict__ x, const float* __restrict__ y,
    const int* __restrict__ mask,
    float* __restrict__ minarr, float* __restrict__ out)
{
    const int qt  = blockIdx.x & 1;   // query tile (2048 queries each)
    const int sc  = blockIdx.x >> 1;  // set chunk 0..15
    const int b   = blockIdx.y;
    const int dir = blockIdx.z;

    const float* Q = (dir == 0 ? x : y) + (size_t)b * 3 * N;
    const float* S = (dir == 0 ? y : x) + (size_t)b * 3 * N;

    // stage + pack this block's 256 set points into LDS (one point/thread)
    __shared__ float4 w[SCHUNK];
    {
        int j = sc * SCHUNK + threadIdx.x;
        float s0 = S[j], s1 = S[N + j], s2 = S[2 * N + j];
        float madd = mask[b * N + j] ? 0.0f : BIG_F;
        float4 p;
        p.x = -2.0f * s0; p.y = -2.0f * s1; p.z = -2.0f * s2;
        p.w = fmaf(s2, s2, fmaf(s1, s1, s0 * s0)) + madd;
        w[threadIdx.x] = p;
    }
    // zero the output once (finalize runs in the NEXT dispatch -> no race)
    if (blockIdx.x == 0 && blockIdx.y == 0 && blockIdx.z == 0 && threadIdx.x == 0)
        out[0] = 0.0f;
    __syncthreads();

    float qx[QPT], qy[QPT], qz[QPT], m[QPT];
    const int qbase = qt * 2048 + threadIdx.x;
#pragma unroll
    for (int k = 0; k < QPT; ++k) {
        int q = qbase + k * 256;
        qx[k] = Q[q]; qy[k] = Q[N + q]; qz[k] = Q[2 * N + q];
        m[k] = 1e30f;
    }

    // inner loop: broadcast LDS reads (conflict-free), 32 VALU ops per point
#pragma unroll 4
    for (int p = 0; p < SCHUNK; ++p) {
        float4 wp = w[p];
#pragma unroll
        for (int k = 0; k < QPT; ++k)
            m[k] = fminf(m[k],
                fmaf(qx[k], wp.x, fmaf(qy[k], wp.y, fmaf(qz[k], wp.z, wp.w))));
    }

    // exclusive partial-min slot per (dir,b,sc,q): plain store, no init needed
    float* Mrow = minarr + ((((size_t)dir * B + b) * NSC + sc) << 12) + qbase;
#pragma unroll
    for (int k = 0; k < QPT; ++k) {
        float qq = fmaf(qz[k], qz[k], fmaf(qy[k], qy[k], qx[k] * qx[k]));
        Mrow[k * 256] = qq + m[k];
    }
}

__global__ __launch_bounds__(256) void finalize_kernel(
    const int* __restrict__ mask, const float* __restrict__ minarr,
    float* __restrict__ out)
{
    const int b = blockIdx.x & 15, dir = blockIdx.x >> 4;
    const float* base = minarr + (((size_t)dir * B + b) * NSC << 12);
    const int4* mrow = (const int4*)(mask + b * N);

    float s = 0.0f, c = 0.0f;
#pragma unroll
    for (int pass = 0; pass < 4; ++pass) {
        int g = threadIdx.x + pass * 256;      // float4 group index, 1024/pass
        float4 mn = ((const float4*)base)[g];
#pragma unroll
        for (int sc = 1; sc < NSC; ++sc) {
            float4 v = ((const float4*)(base + ((size_t)sc << 12)))[g];
            mn.x = fminf(mn.x, v.x); mn.y = fminf(mn.y, v.y);
            mn.z = fminf(mn.z, v.z); mn.w = fminf(mn.w, v.w);
        }
        int4 mk = mrow[g];
        if (mk.x) { s += mn.x; c += 1.0f; }
        if (mk.y) { s += mn.y; c += 1.0f; }
        if (mk.z) { s += mn.z; c += 1.0f; }
        if (mk.w) { s += mn.w; c += 1.0f; }
    }
    for (int off = 32; off > 0; off >>= 1) {
        s += __shfl_down(s, off);
        c += __shfl_down(c, off);
    }
    __shared__ float rs[4], rc[4];
    const int wv = threadIdx.x >> 6;
    if ((threadIdx.x & 63) == 0) { rs[wv] = s; rc[wv] = c; }
    __syncthreads();
    if (threadIdx.x == 0) {
        float S = rs[0] + rs[1] + rs[2] + rs[3];
        float C = rc[0] + rc[1] + rc[2] + rc[3];
        atomicAdd(out, (S / C) * (1.0f / (float)B));
    }
}

extern "C" void kernel_launch(void* const* d_in, const int* in_sizes, int n_in,
                              void* d_out, int out_size, void* d_ws, size_t ws_size,
                              hipStream_t stream) {
    const float* x    = (const float*)d_in[0];
    const float* y    = (const float*)d_in[1];
    const int*   mask = (const int*)d_in[2];

    float* minarr = (float*)d_ws;  // 2*B*NSC*N floats = 8 MB

    chamfer_main<<<dim3(2 * NSC, B, 2), 256, 0, stream>>>(
        x, y, mask, minarr, (float*)d_out);
    finalize_kernel<<<dim3(2 * B), 256, 0, stream>>>(
        mask, minarr, (float*)d_out);
}

// Round 8
// 103.542 us; speedup vs baseline: 3.3526x; 1.0019x over previous
//
#include <hip/hip_runtime.h>

#define BIG_F 1e10f
constexpr int B = 16;
constexpr int N = 4096;
constexpr int QPT = 4;       // 256 threads x 4 = 1024 queries per block
constexpr int SCHUNK = 256;  // set points staged in LDS per block
constexpr int NSC = N / SCHUNK;  // 16 chunks

// pack per set point j: { -2*s0, -2*s1, -2*s2, s.s + (valid ? 0 : BIG) }
// dist(q,j) = qq + dot(q, pack.xyz) + pack.w; qq hoists out of the min.

__global__ __launch_bounds__(256) void chamfer_main(
    const float* __restrict__ x, const float* __restrict__ y,
    const int* __restrict__ mask,
    float* __restrict__ minarr, float* __restrict__ out)
{
    const int qt  = blockIdx.x & 3;   // query tile 0..3 (1024 queries each)
    const int sc  = blockIdx.x >> 2;  // set chunk 0..15
    const int b   = blockIdx.y;
    const int dir = blockIdx.z;

    const float* Q = (dir == 0 ? x : y) + (size_t)b * 3 * N;
    const float* S = (dir == 0 ? y : x) + (size_t)b * 3 * N;

    // stage + pack this block's 256 set points into LDS (one point/thread)
    __shared__ float4 w[SCHUNK];
    {
        int j = sc * SCHUNK + threadIdx.x;
        float s0 = S[j], s1 = S[N + j], s2 = S[2 * N + j];
        float madd = mask[b * N + j] ? 0.0f : BIG_F;
        float4 p;
        p.x = -2.0f * s0; p.y = -2.0f * s1; p.z = -2.0f * s2;
        p.w = fmaf(s2, s2, fmaf(s1, s1, s0 * s0)) + madd;
        w[threadIdx.x] = p;
    }
    // zero the output once (finalize runs in the NEXT dispatch -> no race)
    if (blockIdx.x == 0 && blockIdx.y == 0 && blockIdx.z == 0 && threadIdx.x == 0)
        out[0] = 0.0f;
    __syncthreads();

    float qx[QPT], qy[QPT], qz[QPT], m[QPT];
    const int qbase = qt * 1024 + threadIdx.x;
#pragma unroll
    for (int k = 0; k < QPT; ++k) {
        int q = qbase + k * 256;
        qx[k] = Q[q]; qy[k] = Q[N + q]; qz[k] = Q[2 * N + q];
        m[k] = 1e30f;
    }

    // inner loop: 2 points per step; min(m, min(d0,d1)) -> v_min3_f32.
    // 7 VALU insts per 2 pairs per query (vs 8 for sequential min).
#pragma unroll 4
    for (int p = 0; p < SCHUNK; p += 2) {
        float4 w0 = w[p];
        float4 w1 = w[p + 1];
#pragma unroll
        for (int k = 0; k < QPT; ++k) {
            float d0 = fmaf(qx[k], w0.x, fmaf(qy[k], w0.y, fmaf(qz[k], w0.z, w0.w)));
            float d1 = fmaf(qx[k], w1.x, fmaf(qy[k], w1.y, fmaf(qz[k], w1.z, w1.w)));
            m[k] = fminf(m[k], fminf(d0, d1));
        }
    }

    // exclusive partial-min slot per (dir,b,sc,q): plain store, no init needed
    float* Mrow = minarr + ((((size_t)dir * B + b) * NSC + sc) << 12) + qbase;
#pragma unroll
    for (int k = 0; k < QPT; ++k) {
        float qq = fmaf(qz[k], qz[k], fmaf(qy[k], qy[k], qx[k] * qx[k]));
        Mrow[k * 256] = qq + m[k];
    }
}

__global__ __launch_bounds__(256) void finalize_kernel(
    const int* __restrict__ mask, const float* __restrict__ minarr,
    float* __restrict__ out)
{
    const int b = blockIdx.x & 15, dir = blockIdx.x >> 4;
    const float* base = minarr + (((size_t)dir * B + b) * NSC << 12);
    const int4* mrow = (const int4*)(mask + b * N);

    float s = 0.0f, c = 0.0f;
#pragma unroll
    for (int pass = 0; pass < 4; ++pass) {
        int g = threadIdx.x + pass * 256;      // float4 group index
        float4 mn = ((const float4*)base)[g];
#pragma unroll
        for (int sc = 1; sc < NSC; ++sc) {
            float4 v = ((const float4*)(base + ((size_t)sc << 12)))[g];
            mn.x = fminf(mn.x, v.x); mn.y = fminf(mn.y, v.y);
            mn.z = fminf(mn.z, v.z); mn.w = fminf(mn.w, v.w);
        }
        int4 mk = mrow[g];
        if (mk.x) { s += mn.x; c += 1.0f; }
        if (mk.y) { s += mn.y; c += 1.0f; }
        if (mk.z) { s += mn.z; c += 1.0f; }
        if (mk.w) { s += mn.w; c += 1.0f; }
    }
    for (int off = 32; off > 0; off >>= 1) {
        s += __shfl_down(s, off);
        c += __shfl_down(c, off);
    }
    __shared__ float rs[4], rc[4];
    const int wv = threadIdx.x >> 6;
    if ((threadIdx.x & 63) == 0) { rs[wv] = s; rc[wv] = c; }
    __syncthreads();
    if (threadIdx.x == 0) {
        float S = rs[0] + rs[1] + rs[2] + rs[3];
        float C = rc[0] + rc[1] + rc[2] + rc[3];
        atomicAdd(out, (S / C) * (1.0f / (float)B));
    }
}

extern "C" void kernel_launch(void* const* d_in, const int* in_sizes, int n_in,
                              void* d_out, int out_size, void* d_ws, size_t ws_size,
                              hipStream_t stream) {
    const float* x    = (const float*)d_in[0];
    const float* y    = (const float*)d_in[1];
    const int*   mask = (const int*)d_in[2];

    float* minarr = (float*)d_ws;  // 2*B*NSC*4096 floats = 8 MB

    chamfer_main<<<dim3(4 * NSC, B, 2), 256, 0, stream>>>(
        x, y, mask, minarr, (float*)d_out);
    finalize_kernel<<<dim3(2 * B), 256, 0, stream>>>(
        mask, minarr, (float*)d_out);
}

// Round 9
// 96.038 us; speedup vs baseline: 3.6146x; 1.0781x over previous
//
#include <hip/hip_runtime.h>

typedef short bf16x8 __attribute__((ext_vector_type(8)));
typedef float f32x4  __attribute__((ext_vector_type(4)));

#define BIG_F 1e10f
constexpr int B = 16;
constexpr int N = 4096;
constexpr int ROWS = 256;        // rows (x-points) per block
constexpr int COLS = 512;        // cols (y-points) per block
constexpr int NRB = N / ROWS;    // 16 row-blocks
constexpr int NCB = N / COLS;    // 8 col-blocks

// truncating bf16 hi/lo split: v ~= hi + lo with |v-hi-lo| <= 2^-16 |v|
__device__ __forceinline__ void split(float v, unsigned short& h, unsigned short& l) {
    unsigned hb = __float_as_uint(v) & 0xFFFF0000u;
    h = (unsigned short)(hb >> 16);
    float r = v - __uint_as_float(hb);
    l = (unsigned short)(__float_as_uint(r) >> 16);
}

__device__ __forceinline__ float min3f(float a, float b, float c) {
    return fminf(fminf(a, b), c);
}

// P[n,m] = xx[n] + yy[m] - 2 x_n . y_m  (+BIG on masked n rows / m cols), via one
// mfma_f32_16x16x32_bf16 per 16x16 tile:
//   A_k(n) = [ah0..2, ah0..2, al0..2, al0..2, xxh, xxl, 1, 1]   (ah+al = -2x)
//   B_k(m) = [yh0..2, yl0..2, yh0..2, yl0..2, 1, 1, yyh, yyl]
// K=16 used, K=16..31 zero (quads 2,3 load nothing).
__global__ __launch_bounds__(256) void chamfer_mfma(
    const float* __restrict__ x, const float* __restrict__ y,
    const int* __restrict__ mask,
    float* __restrict__ rowpart,   // [B][NCB][N]  exclusive slots (no init needed)
    float* __restrict__ colpart,   // [B][NRB][N]
    float* __restrict__ out)
{
    const int rb = blockIdx.x & 15;   // row-block 0..15
    const int cb = blockIdx.x >> 4;   // col-block 0..7
    const int b  = blockIdx.y;
    const int t  = threadIdx.x;

    __shared__ unsigned short Apack[ROWS * 16];  // 8 KB
    __shared__ unsigned short Bpack[COLS * 16];  // 16 KB
    __shared__ float colbuf[4][COLS];            // 8 KB

    if (blockIdx.x == 0 && b == 0 && t == 0) out[0] = 0.0f;  // finalize is next dispatch

    const unsigned short one = 0x3F80;  // bf16 1.0

    // ---- pack A: this block's 256 x-points ----
    {
        int n = rb * ROWS + t;
        const float* xb = x + (size_t)b * 3 * N;
        float x0 = xb[n], x1 = xb[N + n], x2 = xb[2 * N + n];
        float madd = mask[b * N + n] ? 0.0f : BIG_F;
        float xx = fmaf(x2, x2, fmaf(x1, x1, x0 * x0)) + madd;
        unsigned short ah0, al0, ah1, al1, ah2, al2, xh, xl;
        split(-2.0f * x0, ah0, al0);
        split(-2.0f * x1, ah1, al1);
        split(-2.0f * x2, ah2, al2);
        split(xx, xh, xl);
        unsigned short* p = &Apack[t * 16];
        p[0] = ah0; p[1] = ah1; p[2] = ah2; p[3] = ah0; p[4] = ah1; p[5] = ah2;
        p[6] = al0; p[7] = al1; p[8] = al2; p[9] = al0; p[10] = al1; p[11] = al2;
        p[12] = xh; p[13] = xl; p[14] = one; p[15] = one;
    }
    // ---- pack B: this block's 512 y-points (2 per thread) ----
#pragma unroll
    for (int i = 0; i < 2; ++i) {
        int c = t + i * 256;
        int m = cb * COLS + c;
        const float* yb = y + (size_t)b * 3 * N;
        float y0 = yb[m], y1 = yb[N + m], y2 = yb[2 * N + m];
        float madd = mask[b * N + m] ? 0.0f : BIG_F;
        float yy = fmaf(y2, y2, fmaf(y1, y1, y0 * y0)) + madd;
        unsigned short yh0, yl0, yh1, yl1, yh2, yl2, qh, ql;
        split(y0, yh0, yl0);
        split(y1, yh1, yl1);
        split(y2, yh2, yl2);
        split(yy, qh, ql);
        unsigned short* p = &Bpack[c * 16];
        p[0] = yh0; p[1] = yh1; p[2] = yh2; p[3] = yl0; p[4] = yl1; p[5] = yl2;
        p[6] = yh0; p[7] = yh1; p[8] = yh2; p[9] = yl0; p[10] = yl1; p[11] = yl2;
        p[12] = one; p[13] = one; p[14] = qh; p[15] = ql;
    }
    __syncthreads();

    const int w  = t >> 6;    // wave 0..3 (owns rows w*64..w*64+63)
    const int L  = t & 63;
    const int lq = L >> 4;    // quad 0..3
    const int lc = L & 15;

    const bf16x8 zero8 = {0, 0, 0, 0, 0, 0, 0, 0};
    const f32x4  zf4   = {0.f, 0.f, 0.f, 0.f};

    // A-frags: 4 row-subtiles; lane holds A[m=lc][k=lq*8+j]; quads 2,3 = zero pad
    bf16x8 afr[4];
#pragma unroll
    for (int s = 0; s < 4; ++s) {
        afr[s] = zero8;
        if (lq < 2)
            afr[s] = *(const bf16x8*)&Apack[(w * 64 + s * 16 + lc) * 16 + lq * 8];
    }

    float rm[4][4];
#pragma unroll
    for (int s = 0; s < 4; ++s)
#pragma unroll
        for (int r = 0; r < 4; ++r) rm[s][r] = 1e30f;

    for (int cc = 0; cc < 16; ++cc) {   // 32-col double-chunks over block's 512 cols
        const int c0 = cc * 32 + lc;
        bf16x8 bf0 = zero8, bf1 = zero8;
        if (lq < 2) {
            bf0 = *(const bf16x8*)&Bpack[c0 * 16 + lq * 8];
            bf1 = *(const bf16x8*)&Bpack[(c0 + 16) * 16 + lq * 8];
        }
        f32x4 C0[4], C1[4];
#pragma unroll
        for (int s = 0; s < 4; ++s) {
            C0[s] = __builtin_amdgcn_mfma_f32_16x16x32_bf16(afr[s], bf0, zf4, 0, 0, 0);
            C1[s] = __builtin_amdgcn_mfma_f32_16x16x32_bf16(afr[s], bf1, zf4, 0, 0, 0);
        }
        // row-mins: C[s][r] is row (w*64 + s*16 + lq*4 + r), accumulated over cols
        float v0 = 1e30f, v1 = 1e30f;
#pragma unroll
        for (int s = 0; s < 4; ++s)
#pragma unroll
            for (int r = 0; r < 4; ++r) {
                rm[s][r] = min3f(rm[s][r], C0[s][r], C1[s][r]);
                v0 = fminf(v0, C0[s][r]);
                v1 = fminf(v1, C1[s][r]);
            }
        // col-mins: combine the 4 quads (rows lq*4+r) -> min over this wave's 64 rows
        v0 = fminf(v0, __shfl_xor(v0, 16));
        v0 = fminf(v0, __shfl_xor(v0, 32));
        v1 = fminf(v1, __shfl_xor(v1, 16));
        v1 = fminf(v1, __shfl_xor(v1, 32));
        if (lq == 0) {
            colbuf[w][cc * 32 + lc] = v0;
            colbuf[w][cc * 32 + 16 + lc] = v1;
        }
    }

    // finish row-mins: reduce across the 16 col-lanes
#pragma unroll
    for (int off = 1; off <= 8; off <<= 1)
#pragma unroll
        for (int s = 0; s < 4; ++s)
#pragma unroll
            for (int r = 0; r < 4; ++r)
                rm[s][r] = fminf(rm[s][r], __shfl_xor(rm[s][r], off));
    if (lc == 0) {
        float* rp = rowpart + ((size_t)b * NCB + cb) * N + rb * ROWS + w * 64;
#pragma unroll
        for (int s = 0; s < 4; ++s)
#pragma unroll
            for (int r = 0; r < 4; ++r)
                rp[s * 16 + lq * 4 + r] = rm[s][r];
    }

    __syncthreads();
    // combine the 4 waves' col-mins -> block's col partial (min over 256 rows)
    for (int c = t; c < COLS; c += 256) {
        float v = fminf(fminf(colbuf[0][c], colbuf[1][c]),
                        fminf(colbuf[2][c], colbuf[3][c]));
        colpart[((size_t)b * NRB + rb) * N + cb * COLS + c] = v;
    }
}

__global__ __launch_bounds__(256) void finalize_kernel(
    const int* __restrict__ mask,
    const float* __restrict__ rowpart, const float* __restrict__ colpart,
    float* __restrict__ out)
{
    const int b   = blockIdx.x & 15;
    const int dir = (blockIdx.x >> 4) & 1;
    const int q   = blockIdx.x >> 5;   // quarter 0..3
    const int t   = threadIdx.x;
    const int* mrow = mask + b * N;

    // full-batch valid count (cheap, L2-resident)
    int cnt = 0;
    for (int i = t; i < N / 4; i += 256) {
        int4 mk = ((const int4*)mrow)[i];
        cnt += mk.x + mk.y + mk.z + mk.w;
    }

    const float* base = dir ? (colpart + (size_t)b * NRB * N)
                            : (rowpart + (size_t)b * NCB * N);
    const int npb = dir ? NRB : NCB;

    const int p0 = q * 1024 + t * 4;
    float4 mn = *(const float4*)(base + p0);
    for (int pb = 1; pb < npb; ++pb) {
        float4 v = *(const float4*)(base + (size_t)pb * N + p0);
        mn.x = fminf(mn.x, v.x); mn.y = fminf(mn.y, v.y);
        mn.z = fminf(mn.z, v.z); mn.w = fminf(mn.w, v.w);
    }
    int4 mk = *(const int4*)(mrow + p0);
    float s = (mk.x ? mn.x : 0.f) + (mk.y ? mn.y : 0.f)
            + (mk.z ? mn.z : 0.f) + (mk.w ? mn.w : 0.f);

    for (int off = 32; off > 0; off >>= 1) {
        s   += __shfl_down(s, off);
        cnt += __shfl_down(cnt, off);
    }
    __shared__ float rs[4];
    __shared__ int   rc[4];
    const int wv = t >> 6;
    if ((t & 63) == 0) { rs[wv] = s; rc[wv] = cnt; }
    __syncthreads();
    if (t == 0) {
        float S = rs[0] + rs[1] + rs[2] + rs[3];
        float C = (float)(rc[0] + rc[1] + rc[2] + rc[3]);
        atomicAdd(out, (S / C) * (1.0f / 16.0f));
    }
}

extern "C" void kernel_launch(void* const* d_in, const int* in_sizes, int n_in,
                              void* d_out, int out_size, void* d_ws, size_t ws_size,
                              hipStream_t stream) {
    const float* x    = (const float*)d_in[0];
    const float* y    = (const float*)d_in[1];
    const int*   mask = (const int*)d_in[2];

    float* rowpart = (float*)d_ws;                    // B*NCB*N floats = 2 MB
    float* colpart = rowpart + (size_t)B * NCB * N;   // B*NRB*N floats = 4 MB

    chamfer_mfma<<<dim3(NRB * NCB, B), 256, 0, stream>>>(
        x, y, mask, rowpart, colpart, (float*)d_out);
    finalize_kernel<<<dim3(128), 256, 0, stream>>>(
        mask, rowpart, colpart, (float*)d_out);
}